// Round 1
// baseline (321.220 us; speedup 1.0000x reference)
//
#include <hip/hip_runtime.h>
#include <hip/hip_bf16.h>

// GaussianSmoothing: x (2,1,192,192,192) f32, separable Gaussian K=13 sigma=2.
// Implemented as three 1-D 13-tap passes (W, H, D axes), zero-padded.
// Ping-pong: x -> d_out (W pass) -> d_ws (H pass) -> d_out (D pass).

#define DIM 192
#define DIM2 (192 * 192)        // 36864
#define TOTAL (2 * 192 * 192 * 192)  // 14,155,776 elements

// g(x) = 1/(2*sqrt(2*pi)) * exp(-x^2/8), x = -6..6  (sigma = 2)
// Values computed in double precision, rounded to fp32; reference computes the
// same function in fp32 numpy — difference is ~1 ulp, threshold is 5.8e-3.
__device__ __forceinline__ const float* gauss_taps() {
    static const __device__ float G[13] = {
        2.2159242e-03f,  // exp(-4.5)   * 0.19947114
        8.7641505e-03f,  // exp(-3.125) * 0.19947114
        2.6995483e-02f,  // exp(-2.0)   * 0.19947114
        6.4758800e-02f,  // exp(-1.125) * 0.19947114
        1.2098536e-01f,  // exp(-0.5)   * 0.19947114
        1.7603266e-01f,  // exp(-0.125) * 0.19947114
        1.9947114e-01f,  // exp(0)      * 0.19947114
        1.7603266e-01f,
        1.2098536e-01f,
        6.4758800e-02f,
        2.6995483e-02f,
        8.7641505e-03f,
        2.2159242e-03f,
    };
    return G;
}

// AXIS: 0 = W (stride 1), 1 = H (stride 192), 2 = D (stride 192*192).
// Batch dim (2) rides along in the flat index; conv never crosses the D
// boundary of one image because coord is derived per-axis and the (k-6)*stride
// offset stays within the same image whenever 0 <= coord+k-6 < 192.
template <int AXIS>
__global__ void blur_pass(const float* __restrict__ in, float* __restrict__ out) {
    const float* G = gauss_taps();
    int idx = blockIdx.x * blockDim.x + threadIdx.x;
    if (idx >= TOTAL) return;

    int coord, stride;
    if (AXIS == 0) {
        coord = idx % DIM;
        stride = 1;
    } else if (AXIS == 1) {
        coord = (idx / DIM) % DIM;
        stride = DIM;
    } else {
        coord = (idx / DIM2) % DIM;
        stride = DIM2;
    }

    float acc = 0.0f;
#pragma unroll
    for (int k = 0; k < 13; ++k) {
        int c = coord + k - 6;
        if (c >= 0 && c < DIM) {
            acc += G[k] * in[idx + (k - 6) * stride];
        }
    }
    out[idx] = acc;
}

extern "C" void kernel_launch(void* const* d_in, const int* in_sizes, int n_in,
                              void* d_out, int out_size, void* d_ws, size_t ws_size,
                              hipStream_t stream) {
    const float* x = (const float*)d_in[0];
    float* out = (float*)d_out;
    float* tmp = (float*)d_ws;  // needs TOTAL*4 = 56.6 MB of workspace

    const int block = 256;
    const int grid = (TOTAL + block - 1) / block;

    // Pass 1: W axis, x -> out
    blur_pass<0><<<grid, block, 0, stream>>>(x, out);
    // Pass 2: H axis, out -> tmp
    blur_pass<1><<<grid, block, 0, stream>>>(out, tmp);
    // Pass 3: D axis, tmp -> out
    blur_pass<2><<<grid, block, 0, stream>>>(tmp, out);
}

// Round 2
// 63.325 us; speedup vs baseline: 5.0725x; 5.0725x over previous
//
#include <hip/hip_runtime.h>
#include <hip/hip_bf16.h>

// GaussianSmoothing (2,1,192,192,192) f32, separable K=13 sigma=2.
// Pass 1 blur_w: row-staged-in-LDS, x -> d_out
// Pass 2 blur_h: column-march rolling accumulators (stride = 192), d_out -> d_ws
// Pass 3 blur_d: column-march rolling accumulators (stride = 192*192), d_ws -> d_out

#define DIM 192
#define DIM2 (192 * 192)
#define NIMG 2
#define TOTAL (NIMG * DIM * DIM2)   // 14,155,776 floats

#define GTAPS                                                     \
    constexpr float G[13] = {                                     \
        2.2159242e-03f, 8.7641505e-03f, 2.6995483e-02f,           \
        6.4758800e-02f, 1.2098536e-01f, 1.7603266e-01f,           \
        1.9947114e-01f, 1.7603266e-01f, 1.2098536e-01f,           \
        6.4758800e-02f, 2.6995483e-02f, 8.7641505e-03f,           \
        2.2159242e-03f };

// ---------------------------------------------------------------------------
// Pass 1: blur along W (stride 1). Block = 256 threads, handles 768 contiguous
// floats = exactly 4 rows of 192. Rows staged in LDS with 8-elem zero pads on
// each side (16B-aligned float4 stores). Grid = TOTAL/768 = 18432 blocks.
// ---------------------------------------------------------------------------
__global__ __launch_bounds__(256) void blur_w(const float* __restrict__ in,
                                              float* __restrict__ out) {
    GTAPS
    __shared__ float lds[4 * 208];  // 4 rows, 8 + 192 + 8
    const int t = threadIdx.x;
    const int base = blockIdx.x * 768;

    // zero the pads: 4 rows x (8 left + 8 right) = 64 entries
    if (t < 64) {
        int r = t >> 4;
        int c = t & 15;
        int col = (c < 8) ? c : (192 + c);  // 0..7 or 200..207
        lds[r * 208 + col] = 0.0f;
    }
    // stage 768 floats as 192 float4 (16B-aligned in LDS: 208r + 8 + 4j)
    if (t < 192) {
        float4 v = ((const float4*)(in + base))[t];
        int r = t / 48;
        int c4 = t % 48;
        *(float4*)&lds[r * 208 + 8 + c4 * 4] = v;
    }
    __syncthreads();

#pragma unroll
    for (int m = 0; m < 3; ++m) {
        int e = t + m * 256;           // 0..767
        int r = e / 192;
        int w = e % 192;
        const float* p = &lds[r * 208 + 2 + w];  // p[k] = in(w + k - 6), zero-padded
        float acc = 0.0f;
#pragma unroll
        for (int k = 0; k < 13; ++k) acc += G[k] * p[k];
        out[base + e] = acc;
    }
}

// ---------------------------------------------------------------------------
// Passes 2/3: blur along an axis with element-stride S*4 (S in float4 units).
// Each thread owns one float4 "column" and marches a D-chunk of 32 outputs
// (+12 halo inputs) with 13 rolling float4 accumulators (fully unrolled so the
// shift-register becomes pure renaming).
//   column c: base_f4 = (c / Q) * M + (c % Q)
//   H pass: Q=48 (w-quads/row),   M=9216 (plane, f4), S=48 (row, f4)
//   D pass: Q=9216 (quads/plane), M=1769472 (image, f4), S=9216 (plane, f4)
// ncols = 18432 for both; chunks = 6; block = 128 -> grid = 6*18432/128 = 864.
// ---------------------------------------------------------------------------
template <int Q, int M, int S>
__global__ __launch_bounds__(128) void col_blur(const float4* __restrict__ in,
                                                float4* __restrict__ out) {
    GTAPS
    const int gt = blockIdx.x * 128 + threadIdx.x;
    const int chunk = gt / 18432;          // uniform per block (18432 % 128 == 0)
    const int c = gt % 18432;
    const int base = (c / Q) * M + (c % Q);
    const int d0 = chunk * 32;

    float4 acc[13];
#pragma unroll
    for (int j = 0; j < 13; ++j) acc[j] = make_float4(0.f, 0.f, 0.f, 0.f);

#pragma unroll
    for (int s = 0; s < 44; ++s) {
        const int i = d0 - 6 + s;        // input position along the axis
        float4 v = make_float4(0.f, 0.f, 0.f, 0.f);
        if (i >= 0 && i < DIM) v = in[base + i * S];   // scalar (uniform) branch
#pragma unroll
        for (int j = 0; j < 13; ++j) {
            const float g = G[12 - j];   // acc[j] is output (i-6)+j, tap = 12-j
            acc[j].x += g * v.x;
            acc[j].y += g * v.y;
            acc[j].z += g * v.z;
            acc[j].w += g * v.w;
        }
        if (s >= 12) out[base + (i - 6) * S] = acc[0];  // compile-time predicate
#pragma unroll
        for (int j = 0; j < 12; ++j) acc[j] = acc[j + 1];
        acc[12] = make_float4(0.f, 0.f, 0.f, 0.f);
    }
}

extern "C" void kernel_launch(void* const* d_in, const int* in_sizes, int n_in,
                              void* d_out, int out_size, void* d_ws, size_t ws_size,
                              hipStream_t stream) {
    const float* x = (const float*)d_in[0];
    float* out = (float*)d_out;
    float* tmp = (float*)d_ws;  // 56.6 MB scratch

    // Pass 1: W axis, x -> out (18432 blocks x 256)
    blur_w<<<18432, 256, 0, stream>>>(x, out);
    // Pass 2: H axis (stride 192 floats = 48 f4), out -> tmp
    col_blur<48, 9216, 48><<<864, 128, 0, stream>>>((const float4*)out, (float4*)tmp);
    // Pass 3: D axis (stride 36864 floats = 9216 f4), tmp -> out
    col_blur<9216, 1769472, 9216><<<864, 128, 0, stream>>>((const float4*)tmp, (float4*)out);
}